// Round 3
// baseline (324.193 us; speedup 1.0000x reference)
//
#include <hip/hip_runtime.h>
#include <hip/hip_bf16.h>

// Layout constants
#define NROW 1600     // BS*Q
#define NEG  3200
#define ROWS_FLAT 25600  // BS*T*Q per tensor

__device__ __forceinline__ float bf2f(unsigned v) { return __uint_as_float(v << 16); }
__device__ __forceinline__ ushort f2bf(float f) {
  __hip_bfloat16 h = __float2bfloat16(f);
  return *(ushort*)&h;
}

// Generic loaders: f32 flag selects fp32 vs packed-bf16 interpretation.
// idx is ELEMENT index (multiple of 8 for load8, 4 for load4).
__device__ __forceinline__ void load8(const ushort* p, size_t idx, int f32, float* o) {
  if (f32) {
    const float* q = (const float*)p;
    float4 a = *(const float4*)(q + idx);
    float4 b = *(const float4*)(q + idx + 4);
    o[0]=a.x; o[1]=a.y; o[2]=a.z; o[3]=a.w;
    o[4]=b.x; o[5]=b.y; o[6]=b.z; o[7]=b.w;
  } else {
    uint4 u = *(const uint4*)(p + idx);
    o[0]=bf2f(u.x & 0xffffu); o[1]=bf2f(u.x >> 16);
    o[2]=bf2f(u.y & 0xffffu); o[3]=bf2f(u.y >> 16);
    o[4]=bf2f(u.z & 0xffffu); o[5]=bf2f(u.z >> 16);
    o[6]=bf2f(u.w & 0xffffu); o[7]=bf2f(u.w >> 16);
  }
}
__device__ __forceinline__ void load4(const ushort* p, size_t idx, int f32, float* o) {
  if (f32) {
    float4 a = *(const float4*)((const float*)p + idx);
    o[0]=a.x; o[1]=a.y; o[2]=a.z; o[3]=a.w;
  } else {
    ushort4 v = *(const ushort4*)(p + idx);
    o[0]=bf2f(v.x); o[1]=bf2f(v.y); o[2]=bf2f(v.z); o[3]=bf2f(v.w);
  }
}

// ---------------- K0: dtype detection ----------------
// For each float input, count even-index ushorts whose bf16 exponent field is
// "sane" for an O(1)-scale normal value. bf16 data -> ~64/64; fp32 data read
// as bf16 -> exponent bits are mantissa bits, uniform -> ~10/64.
__global__ void k_detect(const ushort* __restrict__ fe0, const ushort* __restrict__ fe1,
                         const ushort* __restrict__ W, const ushort* __restrict__ bias,
                         int* __restrict__ flags) {
  if (threadIdx.x != 0 || blockIdx.x != 0) return;
  const ushort* ptrs[4] = {fe0, fe1, W, bias};
  for (int t = 0; t < 4; t++) {
    int cnt = 0;
    for (int k = 0; k < 64; k++) {
      unsigned e = ((unsigned)ptrs[t][2*k] >> 7) & 0xffu;
      if (e >= 100u && e <= 140u) cnt++;
    }
    flags[t] = (cnt >= 40) ? 0 : 1;   // 0 = bf16, 1 = fp32
  }
}

// ---------------- K1: projection + L2 normalize ----------------
// Pb layout (bf16): [(src*1600 + b*100 + q)][t][c]  (so neg_all[j] row = Pb + j*16*256)
__global__ __launch_bounds__(256) void k_proj(const ushort* __restrict__ fe0,
    const ushort* __restrict__ fe1, const ushort* __restrict__ W,
    const ushort* __restrict__ bias, const int* __restrict__ flags,
    ushort* __restrict__ Pb) {
  __shared__ float sfe[32][260];
  const int tid = threadIdx.x;
  const int grow0 = blockIdx.x * 32;
  const int src1 = (grow0 >= ROWS_FLAT);
  const ushort* src = src1 ? fe1 : fe0;
  const int fSrc = flags[src1 ? 1 : 0];
  const int fW = flags[2], fB = flags[3];
  const size_t rbase = (size_t)(src1 ? (grow0 - ROWS_FLAT) : grow0) * 256;
  // stage 32 rows x 256 elems -> fp32 LDS
  for (int l = tid; l < 1024; l += 256) {
    int r = l >> 5, kq = (l & 31) << 3;
    float o[8];
    load8(src, rbase + (size_t)r * 256 + kq, fSrc, o);
    *(float4*)&sfe[r][kq]     = *(float4*)&o[0];
    *(float4*)&sfe[r][kq + 4] = *(float4*)&o[4];
  }
  __syncthreads();
  const int wv8 = (tid >> 6) << 3;   // wave owns 8 rows
  const int c0  = (tid & 63) << 2;   // 4 columns
  float bb[4];
  load4(bias, c0, fB, bb);
  float acc[8][4];
  #pragma unroll
  for (int r = 0; r < 8; r++) { acc[r][0]=bb[0]; acc[r][1]=bb[1]; acc[r][2]=bb[2]; acc[r][3]=bb[3]; }
  for (int k = 0; k < 256; k += 4) {
    float wv[4][4];
    #pragma unroll
    for (int kk = 0; kk < 4; kk++)
      load4(W, (size_t)(k + kk) * 256 + c0, fW, wv[kk]);
    #pragma unroll
    for (int r = 0; r < 8; r++) {
      float4 f = *(float4*)&sfe[wv8 + r][k];
      #pragma unroll
      for (int cc = 0; cc < 4; cc++)
        acc[r][cc] += f.x * wv[0][cc] + f.y * wv[1][cc] + f.z * wv[2][cc] + f.w * wv[3][cc];
    }
  }
  #pragma unroll
  for (int r = 0; r < 8; r++) {
    float s = acc[r][0]*acc[r][0] + acc[r][1]*acc[r][1]
            + acc[r][2]*acc[r][2] + acc[r][3]*acc[r][3];
    #pragma unroll
    for (int m = 1; m < 64; m <<= 1) s += __shfl_xor(s, m, 64);
    float inv = 1.0f / sqrtf(s);
    int grow = grow0 + wv8 + r;
    int srcid = grow / ROWS_FLAT;
    int rem   = grow % ROWS_FLAT;
    int b = rem / 1600;
    int t = (rem / 100) & 15;
    int q = rem % 100;
    size_t orow = ((size_t)(srcid * 1600 + b * 100 + q) * 16 + t) * 256;
    ushort4 o;
    o.x = f2bf(acc[r][0]*inv); o.y = f2bf(acc[r][1]*inv);
    o.z = f2bf(acc[r][2]*inv); o.w = f2bf(acc[r][3]*inv);
    *(ushort4*)(Pb + orow + c0) = o;
  }
}

// ---------------- K2a: bridge prep, a-vectors, numer, softplus, bucketing ----------------
__global__ __launch_bounds__(256) void k_bridge(const ushort* __restrict__ Pb,
    const int* __restrict__ bridge, float* __restrict__ A,
    float* __restrict__ prm, float* __restrict__ numer,
    int* __restrict__ cnt, int* __restrict__ lst, float* __restrict__ wsum) {
  int i = blockIdx.x, c = threadIdx.x;
  int bh = bridge[i*3+0], bp = bridge[i*3+1], bt = bridge[i*3+2];
  float bhf = (float)bh, bpf = (float)bp, btf = (float)bt;
  float alpha = (bpf - bhf) / (btf - bhf);
  float sigma = alpha * (btf - bpf);
  const ushort* base = Pb + (size_t)i * 16 * 256;
  float g0 = bf2f(base[bh*256 + c]), g1 = bf2f(base[bp*256 + c]), g2 = bf2f(base[bt*256 + c]);
  float head = bf2f(base[c]), tail = bf2f(base[15*256 + c]);
  float a = (1.0f - alpha) * g0 + alpha * g2;
  float x = g1 - a;
  A[(size_t)i*256 + c] = a;
  float xx = x*x, aac = a*a, sc = head*tail;
  #pragma unroll
  for (int m = 1; m < 64; m <<= 1) {
    xx  += __shfl_xor(xx, m, 64);
    aac += __shfl_xor(aac, m, 64);
    sc  += __shfl_xor(sc, m, 64);
  }
  __shared__ float red[3][4];
  int wv = c >> 6;
  if ((c & 63) == 0) { red[0][wv]=xx; red[1][wv]=aac; red[2][wv]=sc; }
  __syncthreads();
  if (c == 0) {
    float XX = red[0][0]+red[0][1]+red[0][2]+red[0][3];
    float AA = red[1][0]+red[1][1]+red[1][2]+red[1][3];
    float SC = red[2][0]+red[2][1]+red[2][2]+red[2][3];
    float inv2s2 = 1.0f / (2.0f * sigma * sigma);
    prm[i*2+0] = inv2s2;
    prm[i*2+1] = AA;
    numer[i] = expf(-XX * inv2s2);
    float sp = log1pf(expf(0.3f - SC));          // softplus(delta - score)
    atomicAdd(wsum + 1, sp * (1.0f / 1600.0f));
    int pos = atomicAdd(cnt + bp, 1);
    lst[bp * 1600 + pos] = i;
  }
}

// ---------------- K2b: dist = -(1 - 2 a.neg + aa) * inv2s2, grouped by t ----------------
__global__ __launch_bounds__(256) void k_cross(const ushort* __restrict__ Pb,
    const float* __restrict__ A, const float* __restrict__ prm,
    const int* __restrict__ cnt, const int* __restrict__ lst,
    ushort* __restrict__ distb) {
  int t = blockIdx.z;
  int n_t = min(cnt[t], 1600);
  int m0 = blockIdx.y * 32;
  if (m0 >= n_t) return;
  int j0 = blockIdx.x * 128;
  __shared__ float aT[32][68];
  __shared__ float negT[64][129];
  __shared__ int gis[32];
  int tid = threadIdx.x;
  if (tid < 32) {
    int gi = lst[t * 1600 + min(m0 + tid, n_t - 1)];
    gis[tid] = min(max(gi, 0), NROW - 1);
  }
  int tj = tid & 31, ti = tid >> 5;     // ti 0..7 -> 4 i's, tj 0..31 -> 4 j's
  float acc[4][4] = {};
  for (int k0 = 0; k0 < 256; k0 += 64) {
    __syncthreads();
    for (int l = tid; l < 32*16; l += 256) {
      int m = l >> 4, kq = (l & 15) << 2;
      float4 v = *(const float4*)(A + (size_t)gis[m]*256 + k0 + kq);
      *(float4*)&aT[m][kq] = v;
    }
    for (int l = tid; l < 128*8; l += 256) {
      int j = l >> 3, kq = (l & 7) << 3;
      uint4 u = *(const uint4*)(Pb + ((size_t)(j0 + j)*16 + t)*256 + k0 + kq);
      negT[kq+0][j] = bf2f(u.x & 0xffffu); negT[kq+1][j] = bf2f(u.x >> 16);
      negT[kq+2][j] = bf2f(u.y & 0xffffu); negT[kq+3][j] = bf2f(u.y >> 16);
      negT[kq+4][j] = bf2f(u.z & 0xffffu); negT[kq+5][j] = bf2f(u.z >> 16);
      negT[kq+6][j] = bf2f(u.w & 0xffffu); negT[kq+7][j] = bf2f(u.w >> 16);
    }
    __syncthreads();
    #pragma unroll 2
    for (int kk = 0; kk < 64; kk += 4) {
      float4 af[4];
      #pragma unroll
      for (int ii = 0; ii < 4; ii++) af[ii] = *(float4*)&aT[ti*4+ii][kk];
      #pragma unroll
      for (int jj = 0; jj < 4; jj++) {
        int j = tj + jj*32;
        float n0 = negT[kk+0][j], n1 = negT[kk+1][j];
        float n2 = negT[kk+2][j], n3 = negT[kk+3][j];
        #pragma unroll
        for (int ii = 0; ii < 4; ii++)
          acc[ii][jj] += af[ii].x*n0 + af[ii].y*n1 + af[ii].z*n2 + af[ii].w*n3;
      }
    }
  }
  #pragma unroll
  for (int ii = 0; ii < 4; ii++) {
    int ml = ti*4 + ii;
    if (m0 + ml < n_t) {
      int gi = gis[ml];
      float inv2s2 = prm[gi*2], aa = prm[gi*2+1];
      #pragma unroll
      for (int jj = 0; jj < 4; jj++) {
        int j = j0 + tj + jj*32;
        distb[(size_t)gi*NEG + j] = f2bf(-(1.0f - 2.0f*acc[ii][jj] + aa) * inv2s2);
      }
    }
  }
}

// ---------------- K3: top-5 (excl. diag) + brownian loss ----------------
__global__ __launch_bounds__(256) void k_topk(const ushort* __restrict__ distb,
    const float* __restrict__ numer, float* __restrict__ wsum) {
  int i = blockIdx.x, tid = threadIdx.x;
  __shared__ unsigned long long red[256];
  __shared__ float s_self;
  float v[13];
  #pragma unroll
  for (int it = 0; it < 13; it++) {
    int j = tid + it*256;
    float d = (j < NEG) ? bf2f(distb[(size_t)i*NEG + j]) : -1e30f;
    if (j == i) { s_self = d; d = -1e30f; }
    v[it] = d;
  }
  float top[5];
  for (int r = 0; r < 5; r++) {
    float bv = -1e30f; int bi = 0;
    #pragma unroll
    for (int it = 0; it < 13; it++) if (v[it] > bv) { bv = v[it]; bi = it; }
    unsigned u = __float_as_uint(bv);
    u = (u & 0x80000000u) ? ~u : (u | 0x80000000u);
    unsigned long long key = ((unsigned long long)u << 32) | (unsigned)((tid << 8) | bi);
    red[tid] = key;
    for (int s = 128; s > 0; s >>= 1) {
      __syncthreads();
      if (tid < s) { unsigned long long o = red[tid + s]; if (o > red[tid]) red[tid] = o; }
    }
    __syncthreads();
    unsigned long long best = red[0];
    unsigned bu = (unsigned)(best >> 32);
    top[r] = __uint_as_float((bu & 0x80000000u) ? (bu & 0x7fffffffu) : ~bu);
    int widx = (int)(best & 0xffffffffu);
    if (tid == (widx >> 8)) {
      int slot = widx & 0xff;
      #pragma unroll
      for (int it = 0; it < 13; it++) if (it == slot) v[it] = -1e30f;
    }
    __syncthreads();
  }
  if (tid == 0) {
    float deno = expf(s_self);
    #pragma unroll
    for (int r = 0; r < 5; r++) deno += expf(top[r]);
    atomicAdd(wsum + 0, (numer[i] / deno) * (1.0f / 1600.0f));
  }
}

// ---------------- K4: fp32 accumulators -> output (dtype per detected mode) ----------------
__global__ void k_final(const float* __restrict__ wsum, const int* __restrict__ flags,
                        void* __restrict__ out) {
  if (threadIdx.x == 0 && blockIdx.x == 0) {
    if (flags[0]) {            // fp32 mode
      ((float*)out)[0] = wsum[0];
      ((float*)out)[1] = wsum[1];
    } else {                   // bf16 mode
      ushort* o = (ushort*)out;
      o[0] = f2bf(wsum[0]);
      o[1] = f2bf(wsum[1]);
    }
  }
}

extern "C" void kernel_launch(void* const* d_in, const int* in_sizes, int n_in,
                              void* d_out, int out_size, void* d_ws, size_t ws_size,
                              hipStream_t stream) {
  const ushort* fe0   = (const ushort*)d_in[0];
  const ushort* fe1   = (const ushort*)d_in[1];
  const ushort* W     = (const ushort*)d_in[2];
  const ushort* bias  = (const ushort*)d_in[3];
  const int*    bridge = (const int*)d_in[4];

  // Lean workspace layout (~38.2 MB total)
  ushort* Pb   = (ushort*)d_ws;                  // 13,107,200 bf16 (26.2 MB)
  float*  A    = (float*)(Pb + 13107200);        // 409,600 f (1.6 MB)
  float*  prm  = A + 409600;                     // 3,200 f
  float*  numer= prm + 3200;                     // 1,600 f
  float*  wsum = numer + 1600;                   // 4 f
  ushort* distb= (ushort*)(wsum + 4);            // 5,120,000 bf16 (10.2 MB)
  int*    cnt  = (int*)(distb + 5120000);        // 16
  int*    lst  = cnt + 16;                       // 16*1600
  int*    flags= lst + 16*1600;                  // 4

  hipMemsetAsync(wsum, 0, 2 * sizeof(float), stream);
  hipMemsetAsync(cnt, 0, 16 * sizeof(int), stream);

  k_detect<<<1, 64, 0, stream>>>(fe0, fe1, W, bias, flags);
  k_proj  <<<1600, 256, 0, stream>>>(fe0, fe1, W, bias, flags, Pb);
  k_bridge<<<1600, 256, 0, stream>>>(Pb, bridge, A, prm, numer, cnt, lst, wsum);
  k_cross <<<dim3(25, 12, 16), 256, 0, stream>>>(Pb, A, prm, cnt, lst, distb);
  k_topk  <<<1600, 256, 0, stream>>>(distb, numer, wsum);
  k_final <<<1, 64, 0, stream>>>(wsum, flags, d_out);
}

// Round 4
// 240.485 us; speedup vs baseline: 1.3481x; 1.3481x over previous
//
#include <hip/hip_runtime.h>
#include <hip/hip_bf16.h>

#define NROW 1600
#define NEG  3200
#define ROWS_FLAT 25600

using bf16x8 = __attribute__((ext_vector_type(8))) short;
using f32x4  = __attribute__((ext_vector_type(4))) float;

__device__ __forceinline__ float bf2f(unsigned v) { return __uint_as_float(v << 16); }
__device__ __forceinline__ ushort f2bf(float f) {
  __hip_bfloat16 h = __float2bfloat16(f);
  return *(ushort*)&h;
}
__device__ __forceinline__ float load1(const ushort* p, size_t idx, int f32) {
  return f32 ? ((const float*)p)[idx] : bf2f(p[idx]);
}
__device__ __forceinline__ void load8(const ushort* p, size_t idx, int f32, float* o) {
  if (f32) {
    const float* q = (const float*)p;
    float4 a = *(const float4*)(q + idx);
    float4 b = *(const float4*)(q + idx + 4);
    o[0]=a.x; o[1]=a.y; o[2]=a.z; o[3]=a.w;
    o[4]=b.x; o[5]=b.y; o[6]=b.z; o[7]=b.w;
  } else {
    uint4 u = *(const uint4*)(p + idx);
    o[0]=bf2f(u.x & 0xffffu); o[1]=bf2f(u.x >> 16);
    o[2]=bf2f(u.y & 0xffffu); o[3]=bf2f(u.y >> 16);
    o[4]=bf2f(u.z & 0xffffu); o[5]=bf2f(u.z >> 16);
    o[6]=bf2f(u.w & 0xffffu); o[7]=bf2f(u.w >> 16);
  }
}

// ---------------- K0: dtype detection (1 wave, ballot) ----------------
__global__ void k_detect(const ushort* __restrict__ fe0, const ushort* __restrict__ fe1,
                         const ushort* __restrict__ W, const ushort* __restrict__ bias,
                         int* __restrict__ flags) {
  int lane = threadIdx.x & 63;
  const ushort* ptrs[4] = {fe0, fe1, W, bias};
  for (int t = 0; t < 4; t++) {
    unsigned e = ((unsigned)ptrs[t][2*lane] >> 7) & 0xffu;
    bool ok = (e >= 100u && e <= 140u);
    unsigned long long b = __ballot(ok);
    if (lane == 0) flags[t] = (__popcll(b) >= 40) ? 0 : 1;  // 0=bf16, 1=fp32
  }
}

// ---------------- K0b: Wt[n][k] = bf16(W[k][n]) ----------------
__global__ __launch_bounds__(256) void k_prepw(const ushort* __restrict__ W,
    const int* __restrict__ flags, ushort* __restrict__ Wt) {
  int n = blockIdx.x, k = threadIdx.x;
  int fW = flags[2];
  Wt[n*256 + k] = f2bf(load1(W, (size_t)k*256 + n, fW));
}

// ---------------- K1: MFMA projection + L2 normalize ----------------
// Pb layout (bf16): [(src*1600 + b*100 + q)][t][c]
__global__ __launch_bounds__(256) void k_proj(const ushort* __restrict__ fe0,
    const ushort* __restrict__ fe1, const ushort* __restrict__ Wt,
    const ushort* __restrict__ bias, const int* __restrict__ flags,
    ushort* __restrict__ Pb) {
  __shared__ ushort sX[128*256];   // 64 KB, XOR-swizzled: phys_k = k ^ ((r&7)<<3)
  const int tid = threadIdx.x;
  const int w = tid >> 6, lane = tid & 63, q = lane >> 4, m = lane & 15;
  const int grow0 = blockIdx.x * 128;
  const int src1 = (grow0 >= ROWS_FLAT);
  const ushort* src = src1 ? fe1 : fe0;
  const int fSrc = flags[src1 ? 1 : 0];
  const int fB = flags[3];
  const size_t rbase = (size_t)(src1 ? (grow0 - ROWS_FLAT) : grow0) * 256;
  // stage 128 rows x 256 (dtype-aware convert to bf16)
  #pragma unroll
  for (int i = 0; i < 16; i++) {
    int l = tid + i*256;
    int r = l >> 5, kc = l & 31;
    float o[8];
    load8(src, rbase + (size_t)r*256 + kc*8, fSrc, o);
    uint4 u;
    u.x = (unsigned)f2bf(o[0]) | ((unsigned)f2bf(o[1]) << 16);
    u.y = (unsigned)f2bf(o[2]) | ((unsigned)f2bf(o[3]) << 16);
    u.z = (unsigned)f2bf(o[4]) | ((unsigned)f2bf(o[5]) << 16);
    u.w = (unsigned)f2bf(o[6]) | ((unsigned)f2bf(o[7]) << 16);
    *(uint4*)&sX[r*256 + ((kc*8) ^ ((r&7)<<3))] = u;
  }
  __syncthreads();
  // acc init = bias (per column)
  f32x4 acc[2][16];
  #pragma unroll
  for (int nt = 0; nt < 16; nt++) {
    float bb = load1(bias, nt*16 + m, fB);
    f32x4 v = {bb, bb, bb, bb};
    acc[0][nt] = v; acc[1][nt] = v;
  }
  const int r0 = w*32 + m, r1 = r0 + 16;
  for (int k0 = 0; k0 < 256; k0 += 32) {
    bf16x8 a0 = *(const bf16x8*)&sX[r0*256 + ((k0 + q*8) ^ ((r0&7)<<3))];
    bf16x8 a1 = *(const bf16x8*)&sX[r1*256 + ((k0 + q*8) ^ ((r1&7)<<3))];
    #pragma unroll
    for (int nt = 0; nt < 16; nt++) {
      bf16x8 b = *(const bf16x8*)(Wt + (size_t)(nt*16 + m)*256 + k0 + q*8);
      acc[0][nt] = __builtin_amdgcn_mfma_f32_16x16x32_bf16(a0, b, acc[0][nt], 0, 0, 0);
      acc[1][nt] = __builtin_amdgcn_mfma_f32_16x16x32_bf16(a1, b, acc[1][nt], 0, 0, 0);
    }
  }
  // normalize + permuted store. C/D: col = m (lane&15), row = 4q + reg.
  #pragma unroll
  for (int mt = 0; mt < 2; mt++) {
    #pragma unroll
    for (int reg = 0; reg < 4; reg++) {
      float s = 0.f;
      #pragma unroll
      for (int nt = 0; nt < 16; nt++) { float v = acc[mt][nt][reg]; s += v*v; }
      s += __shfl_xor(s, 1, 64); s += __shfl_xor(s, 2, 64);
      s += __shfl_xor(s, 4, 64); s += __shfl_xor(s, 8, 64);
      float inv = 1.0f / sqrtf(s);
      int grow = grow0 + w*32 + mt*16 + 4*q + reg;
      int srcid = grow / ROWS_FLAT;
      int rem   = grow % ROWS_FLAT;
      int b  = rem / 1600;
      int t  = (rem / 100) & 15;
      int qq = rem % 100;
      size_t orow = ((size_t)(srcid*1600 + b*100 + qq) * 16 + t) * 256;
      #pragma unroll
      for (int nt = 0; nt < 16; nt++)
        Pb[orow + nt*16 + m] = f2bf(acc[mt][nt][reg] * inv);
    }
  }
}

// ---------------- K2a: bridge prep (Ab bf16), numer, softplus, bucketing ----------------
__global__ __launch_bounds__(256) void k_bridge(const ushort* __restrict__ Pb,
    const int* __restrict__ bridge, ushort* __restrict__ Ab,
    float* __restrict__ prm, float* __restrict__ numer,
    int* __restrict__ cnt, int* __restrict__ lst, float* __restrict__ wsum) {
  int i = blockIdx.x, c = threadIdx.x;
  int bh = bridge[i*3+0], bp = bridge[i*3+1], bt = bridge[i*3+2];
  float bhf = (float)bh, bpf = (float)bp, btf = (float)bt;
  float alpha = (bpf - bhf) / (btf - bhf);
  float sigma = alpha * (btf - bpf);
  const ushort* base = Pb + (size_t)i * 16 * 256;
  float g0 = bf2f(base[bh*256 + c]), g1 = bf2f(base[bp*256 + c]), g2 = bf2f(base[bt*256 + c]);
  float head = bf2f(base[c]), tail = bf2f(base[15*256 + c]);
  float a = (1.0f - alpha) * g0 + alpha * g2;
  float x = g1 - a;
  Ab[(size_t)i*256 + c] = f2bf(a);
  float xx = x*x, aac = a*a, sc = head*tail;
  #pragma unroll
  for (int mk = 1; mk < 64; mk <<= 1) {
    xx  += __shfl_xor(xx, mk, 64);
    aac += __shfl_xor(aac, mk, 64);
    sc  += __shfl_xor(sc, mk, 64);
  }
  __shared__ float red[3][4];
  int wv = c >> 6;
  if ((c & 63) == 0) { red[0][wv]=xx; red[1][wv]=aac; red[2][wv]=sc; }
  __syncthreads();
  if (c == 0) {
    float XX = red[0][0]+red[0][1]+red[0][2]+red[0][3];
    float AA = red[1][0]+red[1][1]+red[1][2]+red[1][3];
    float SC = red[2][0]+red[2][1]+red[2][2]+red[2][3];
    float inv2s2 = 1.0f / (2.0f * sigma * sigma);
    prm[i*2+0] = inv2s2;
    prm[i*2+1] = AA;
    numer[i] = expf(-XX * inv2s2);
    float sp = log1pf(expf(0.3f - SC));
    atomicAdd(wsum + 1, sp * (1.0f / 1600.0f));
    int pos = atomicAdd(cnt + bp, 1);
    lst[bp * 1600 + pos] = i;
  }
}

// ---------------- K2b: MFMA dist, grouped by t; no LDS staging ----------------
__global__ __launch_bounds__(256) void k_cross(const ushort* __restrict__ Pb,
    const ushort* __restrict__ Ab, const float* __restrict__ prm,
    const int* __restrict__ cnt, const int* __restrict__ lst,
    ushort* __restrict__ distb) {
  int t = blockIdx.z;
  int n_t = min(cnt[t], 1600);
  int m0 = blockIdx.y * 32;
  if (m0 >= n_t) return;
  int j0 = blockIdx.x * 256;
  __shared__ int s_gis[32];
  int tid = threadIdx.x;
  if (tid < 32) {
    int gi = lst[t*1600 + min(m0 + tid, n_t - 1)];
    s_gis[tid] = min(max(gi, 0), NROW - 1);
  }
  __syncthreads();
  const int w = tid >> 6, lane = tid & 63, q = lane >> 4, m = lane & 15;
  const ushort* a0p = Ab + (size_t)s_gis[m] * 256;
  const ushort* a1p = Ab + (size_t)s_gis[16 + m] * 256;
  const ushort* bp[4];
  #pragma unroll
  for (int nt = 0; nt < 4; nt++) {
    int j = min(j0 + w*64 + nt*16 + m, NEG - 1);
    bp[nt] = Pb + ((size_t)j*16 + t) * 256;
  }
  f32x4 acc[2][4];
  #pragma unroll
  for (int mt = 0; mt < 2; mt++)
    #pragma unroll
    for (int nt = 0; nt < 4; nt++) { f32x4 z = {0.f,0.f,0.f,0.f}; acc[mt][nt] = z; }
  for (int k0 = 0; k0 < 256; k0 += 32) {
    bf16x8 a0 = *(const bf16x8*)(a0p + k0 + q*8);
    bf16x8 a1 = *(const bf16x8*)(a1p + k0 + q*8);
    #pragma unroll
    for (int nt = 0; nt < 4; nt++) {
      bf16x8 b = *(const bf16x8*)(bp[nt] + k0 + q*8);
      acc[0][nt] = __builtin_amdgcn_mfma_f32_16x16x32_bf16(a0, b, acc[0][nt], 0, 0, 0);
      acc[1][nt] = __builtin_amdgcn_mfma_f32_16x16x32_bf16(a1, b, acc[1][nt], 0, 0, 0);
    }
  }
  #pragma unroll
  for (int mt = 0; mt < 2; mt++) {
    #pragma unroll
    for (int reg = 0; reg < 4; reg++) {
      int iloc = mt*16 + 4*q + reg;
      if (m0 + iloc < n_t) {
        int gi = s_gis[iloc];
        float inv2s2 = prm[gi*2], aa = prm[gi*2+1];
        #pragma unroll
        for (int nt = 0; nt < 4; nt++) {
          int jj = j0 + w*64 + nt*16 + m;
          if (jj < NEG)
            distb[(size_t)gi*NEG + jj] = f2bf(-(1.0f - 2.0f*acc[mt][nt][reg] + aa) * inv2s2);
        }
      }
    }
  }
}

// ---------------- K3: top-5 via sorted-register merge (1 barrier) ----------------
__device__ __forceinline__ void sort5(float* c) {
  // optimal 9-CE network, descending
  #define CE(i,j) { float hi = fmaxf(c[i], c[j]), lo = fminf(c[i], c[j]); c[i]=hi; c[j]=lo; }
  CE(0,1) CE(3,4) CE(2,4) CE(2,3) CE(1,4) CE(0,3) CE(0,2) CE(1,3) CE(1,2)
  #undef CE
}
__device__ __forceinline__ void ins5(float* t, float v) {
  float hi, lo;
  hi = fmaxf(t[0], v); lo = fminf(t[0], v); t[0] = hi; v = lo;
  hi = fmaxf(t[1], v); lo = fminf(t[1], v); t[1] = hi; v = lo;
  hi = fmaxf(t[2], v); lo = fminf(t[2], v); t[2] = hi; v = lo;
  hi = fmaxf(t[3], v); lo = fminf(t[3], v); t[3] = hi; v = lo;
  t[4] = fmaxf(t[4], v);
}
__global__ __launch_bounds__(256) void k_topk(const ushort* __restrict__ distb,
    const float* __restrict__ numer, float* __restrict__ wsum) {
  int i = blockIdx.x, tid = threadIdx.x;
  __shared__ float s_w[4][5];
  __shared__ float s_self;
  float t[5] = {-1e30f, -1e30f, -1e30f, -1e30f, -1e30f};
  #pragma unroll
  for (int it = 0; it < 13; it++) {
    int j = tid + it*256;
    if (j < NEG) {
      float d = bf2f(distb[(size_t)i*NEG + j]);
      if (j == i) { s_self = d; }
      else ins5(t, d);
    }
  }
  #pragma unroll
  for (int mk = 1; mk < 64; mk <<= 1) {
    float o[5], c[5];
    #pragma unroll
    for (int k = 0; k < 5; k++) o[k] = __shfl_xor(t[k], mk, 64);
    #pragma unroll
    for (int k = 0; k < 5; k++) c[k] = fmaxf(t[k], o[4 - k]);  // bitonic max-step
    sort5(c);
    #pragma unroll
    for (int k = 0; k < 5; k++) t[k] = c[k];
  }
  if ((tid & 63) == 0)
    #pragma unroll
    for (int k = 0; k < 5; k++) s_w[tid >> 6][k] = t[k];
  __syncthreads();
  if (tid == 0) {
    #pragma unroll
    for (int wv = 1; wv < 4; wv++)
      #pragma unroll
      for (int k = 0; k < 5; k++) ins5(t, s_w[wv][k]);
    float deno = expf(s_self);
    #pragma unroll
    for (int k = 0; k < 5; k++) deno += expf(t[k]);
    atomicAdd(wsum + 0, (numer[i] / deno) * (1.0f / 1600.0f));
  }
}

// ---------------- K4: accumulators -> output (dtype per detected mode) ----------------
__global__ void k_final(const float* __restrict__ wsum, const int* __restrict__ flags,
                        void* __restrict__ out) {
  if (threadIdx.x == 0 && blockIdx.x == 0) {
    if (flags[0]) {
      ((float*)out)[0] = wsum[0];
      ((float*)out)[1] = wsum[1];
    } else {
      ushort* o = (ushort*)out;
      o[0] = f2bf(wsum[0]);
      o[1] = f2bf(wsum[1]);
    }
  }
}

extern "C" void kernel_launch(void* const* d_in, const int* in_sizes, int n_in,
                              void* d_out, int out_size, void* d_ws, size_t ws_size,
                              hipStream_t stream) {
  const ushort* fe0    = (const ushort*)d_in[0];
  const ushort* fe1    = (const ushort*)d_in[1];
  const ushort* W      = (const ushort*)d_in[2];
  const ushort* bias   = (const ushort*)d_in[3];
  const int*    bridge = (const int*)d_in[4];

  // workspace (~37.8 MB)
  ushort* Pb    = (ushort*)d_ws;             // 13,107,200
  ushort* Ab    = Pb + 13107200;             // 409,600
  ushort* Wt    = Ab + 409600;               // 65,536
  ushort* distb = Wt + 65536;                // 5,120,000
  float*  prm   = (float*)(distb + 5120000); // 3,200
  float*  numer = prm + 3200;                // 1,600
  float*  wsum  = numer + 1600;              // 4
  int*    cnt   = (int*)(wsum + 4);          // 16
  int*    lst   = cnt + 16;                  // 25,600
  int*    flags = lst + 25600;               // 4

  hipMemsetAsync(wsum, 0, 2 * sizeof(float), stream);
  hipMemsetAsync(cnt, 0, 16 * sizeof(int), stream);

  k_detect<<<1, 64, 0, stream>>>(fe0, fe1, W, bias, flags);
  k_prepw <<<256, 256, 0, stream>>>(W, flags, Wt);
  k_proj  <<<400, 256, 0, stream>>>(fe0, fe1, Wt, bias, flags, Pb);
  k_bridge<<<1600, 256, 0, stream>>>(Pb, bridge, Ab, prm, numer, cnt, lst, wsum);
  k_cross <<<dim3(13, 12, 16), 256, 0, stream>>>(Pb, Ab, prm, cnt, lst, distb);
  k_topk  <<<1600, 256, 0, stream>>>(distb, numer, wsum);
  k_final <<<1, 64, 0, stream>>>(wsum, flags, d_out);
}